// Round 3
// baseline (106.059 us; speedup 1.0000x reference)
//
#include <hip/hip_runtime.h>
#include <math.h>

#define DIM 4096     // D: 12 FWHT stages
#define ROWS 2048    // B
#define LSTR 65      // LDS row stride (64+1): conflict-free both transpose phases

__device__ __forceinline__ float4 f4mul(float4 a, float4 b) {
    return make_float4(a.x * b.x, a.y * b.y, a.z * b.z, a.w * b.w);
}

// 6 stages over bits i = e[0:2) (inside float4) and r = e[8:12) (across regs).
__device__ __forceinline__ void fwht_ri(float4 v[16]) {
#pragma unroll
    for (int j = 0; j < 16; ++j) {
        float4 a = v[j];
        float t0 = a.x + a.y, t1 = a.x - a.y;
        float t2 = a.z + a.w, t3 = a.z - a.w;
        v[j] = make_float4(t0 + t2, t1 + t3, t0 - t2, t1 - t3);
    }
#pragma unroll
    for (int m = 1; m < 16; m <<= 1) {
#pragma unroll
        for (int j = 0; j < 16; ++j) {
            if (!(j & m)) {
                int k = j | m;
                float4 a = v[j], b = v[k];
                v[j] = make_float4(a.x + b.x, a.y + b.y, a.z + b.z, a.w + b.w);
                v[k] = make_float4(a.x - b.x, a.y - b.y, a.z - b.z, a.w - b.w);
            }
        }
    }
}

// 6 stages over bits m = e[2:8) (in-register after transpose).
__device__ __forceinline__ void fwht_m(float f[64]) {
#pragma unroll
    for (int s = 0; s < 6; ++s) {
        const int h = 1 << s;
#pragma unroll
        for (int m = 0; m < 64; ++m) {
            if (!(m & h)) {
                const int k = m | h;
                float a = f[m], b = f[k];
                f[m] = a + b;
                f[k] = a - b;
            }
        }
    }
}

// One wave per row: out = s1 * FWHT( g * FWHT( s2 * x_row ) )
//   g = g_mu + softplus(g_rho) * eps, computed inline (fused, no pre-kernel).
// Layout A: lane l, slot c=4r+i -> e = 256r + 4l + i   (coalesced b128 I/O)
// Layout B: lane l, slot m      -> e = 256(l>>2) + 4m + (l&3)
__global__ void __launch_bounds__(256, 2)
whvi_main(const float* __restrict__ x, const float* __restrict__ s1,
          const float* __restrict__ s2, const float* __restrict__ eps,
          const float* __restrict__ g_mu, const float* __restrict__ g_rho,
          float* __restrict__ out) {
    const int lane = threadIdx.x & 63;
    const int wid  = threadIdx.x >> 6;
    const int row  = blockIdx.x * 4 + wid;        // 512 blocks x 4 waves = 2048 rows

    __shared__ float lds[4 * 64 * LSTR];          // 66.5 KB -> 2 blocks/CU
    float* __restrict__ L = lds + wid * 64 * LSTR; // wave-private: no barriers
                                                   // (per-wave DS pipe is in-order)

    const float4* __restrict__ xr  = (const float4*)(x + (size_t)row * DIM);
    float4* __restrict__       orw = (float4*)(out + (size_t)row * DIM);
    const float4* __restrict__ s2v = (const float4*)s2;
    const float4* __restrict__ s1v = (const float4*)s1;

    float f[64];
    float4* F = (float4*)f;

    // ---- load + s2 scale (layout A) — issued first, 32 b128 loads in flight
#pragma unroll
    for (int r = 0; r < 16; ++r)
        F[r] = f4mul(xr[64 * r + lane], s2v[64 * r + lane]);

    // ---- FWHT1: (i,r) stages
    fwht_ri(F);

    // ---- transpose A->B: write L[l*65+c], read L[m*65+l]  (both 2-way = free)
#pragma unroll
    for (int c = 0; c < 64; ++c)
        L[lane * LSTR + c] = f[c];
#pragma unroll
    for (int m = 0; m < 64; ++m)
        f[m] = L[m * LSTR + lane];

    // ---- FWHT1: m stages (completes FWHT1)
    fwht_m(f);

    // ---- fused g multiply: g[j] = g_mu[j] + softplus(g_rho[j]) * eps[j]
    // j strides 4 per m -> each load instr covers 16x16B segments, L1/L2-hot.
    {
        const int base = 256 * (lane >> 2) + (lane & 3);
#pragma unroll
        for (int m = 0; m < 64; ++m) {
            const int j = base + 4 * m;
            float u  = __expf(g_rho[j]);          // g_rho in [-5,-4]: u ~ 0.01
            float sp = __logf(1.0f + u);          // log1p error ~6e-8 abs: fine
            f[m] *= fmaf(sp, eps[j], g_mu[j]);
        }
    }

    // ---- FWHT2: m stages
    fwht_m(f);

    // ---- transpose B->A: write L[l*65+m], read L[c*65+l]
#pragma unroll
    for (int m = 0; m < 64; ++m)
        L[lane * LSTR + m] = f[m];
#pragma unroll
    for (int c = 0; c < 64; ++c)
        f[c] = L[c * LSTR + lane];

    // ---- FWHT2: (i,r) stages (completes FWHT2)
    fwht_ri(F);

    // ---- s1 scale + coalesced store (layout A)
#pragma unroll
    for (int r = 0; r < 16; ++r)
        orw[64 * r + lane] = f4mul(F[r], s1v[64 * r + lane]);
}

extern "C" void kernel_launch(void* const* d_in, const int* in_sizes, int n_in,
                              void* d_out, int out_size, void* d_ws, size_t ws_size,
                              hipStream_t stream) {
    // setup_inputs order: x, epsilon, s1, s2, g_mu, g_rho
    const float* x     = (const float*)d_in[0];
    const float* eps   = (const float*)d_in[1];
    const float* s1    = (const float*)d_in[2];
    const float* s2    = (const float*)d_in[3];
    const float* g_mu  = (const float*)d_in[4];
    const float* g_rho = (const float*)d_in[5];
    float* out = (float*)d_out;

    // Single fused kernel: 2048 rows, 1 wave/row, 4 waves/block.
    whvi_main<<<ROWS / 4, 256, 0, stream>>>(x, s1, s2, eps, g_mu, g_rho, out);
}

// Round 4
// 104.285 us; speedup vs baseline: 1.0170x; 1.0170x over previous
//
#include <hip/hip_runtime.h>
#include <math.h>

#define DIM 4096     // D: 12 FWHT stages
#define ROWS 2048    // B
#define LSTR 68      // LDS row stride (64+4): lane rows 16B-aligned -> b128 writes;
                     // read bank (4m+lane)%32 -> 2-way = free (m136)

// ---- pre-kernel: g_t in TRANSPOSED (layout-B) order so the mid-pipeline
// multiply is 16 coalesced float4 loads per lane.
// Layout B: lane l, slot m holds element e = 256*(l>>2) + 4*m + (l&3).
// g_t[l*64 + m] = g[e],  g = g_mu + softplus(g_rho)*eps.
__global__ void g_precompute(const float* __restrict__ eps,
                             const float* __restrict__ g_mu,
                             const float* __restrict__ g_rho,
                             float* __restrict__ g_t) {
    int t = blockIdx.x * blockDim.x + threadIdx.x;   // 0..4095
    int l = t >> 6, m = t & 63;
    int j = 256 * (l >> 2) + 4 * m + (l & 3);
    float sp = log1pf(expf(g_rho[j]));               // g_rho in [-5,-4]: safe
    g_t[t] = g_mu[j] + sp * eps[j];
}

__device__ __forceinline__ float4 f4mul(float4 a, float4 b) {
    return make_float4(a.x * b.x, a.y * b.y, a.z * b.z, a.w * b.w);
}

// 6 stages over bits i = e[0:2) (inside float4) and r = e[8:12) (across regs).
__device__ __forceinline__ void fwht_ri(float4 v[16]) {
#pragma unroll
    for (int j = 0; j < 16; ++j) {
        float4 a = v[j];
        float t0 = a.x + a.y, t1 = a.x - a.y;
        float t2 = a.z + a.w, t3 = a.z - a.w;
        v[j] = make_float4(t0 + t2, t1 + t3, t0 - t2, t1 - t3);
    }
#pragma unroll
    for (int m = 1; m < 16; m <<= 1) {
#pragma unroll
        for (int j = 0; j < 16; ++j) {
            if (!(j & m)) {
                int k = j | m;
                float4 a = v[j], b = v[k];
                v[j] = make_float4(a.x + b.x, a.y + b.y, a.z + b.z, a.w + b.w);
                v[k] = make_float4(a.x - b.x, a.y - b.y, a.z - b.z, a.w - b.w);
            }
        }
    }
}

// 6 stages over bits m = e[2:8) (in-register after the transpose).
__device__ __forceinline__ void fwht_m(float f[64]) {
#pragma unroll
    for (int s = 0; s < 6; ++s) {
        const int h = 1 << s;
#pragma unroll
        for (int m = 0; m < 64; ++m) {
            if (!(m & h)) {
                const int k = m | h;
                float a = f[m], b = f[k];
                f[m] = a + b;
                f[k] = a - b;
            }
        }
    }
}

// One wave per row: out = s1 * FWHT( g * FWHT( s2 * x_row ) )
// Layout A: lane l, slot c=4r+i -> e = 256r + 4l + i   (coalesced b128 I/O)
// Layout B: lane l, slot m      -> e = 256(l>>2) + 4m + (l&3)
__global__ void __launch_bounds__(256)
whvi_main(const float* __restrict__ x, const float* __restrict__ s1,
          const float* __restrict__ s2, const float* __restrict__ g_t,
          float* __restrict__ out) {
    const int lane = threadIdx.x & 63;
    const int wid  = threadIdx.x >> 6;
    const int row  = blockIdx.x * 4 + wid;      // 512 blocks x 4 waves = 2048 rows

    __shared__ float lds[4 * 64 * LSTR];        // 69.6 KB -> 2 blocks/CU, 8 waves/CU
    float* __restrict__ L = lds + wid * 64 * LSTR;  // wave-private: no barriers
    float4* __restrict__ L4 = (float4*)(L);         // 16B-aligned lane rows

    const float4* __restrict__ xr  = (const float4*)(x + (size_t)row * DIM);
    float4* __restrict__       orw = (float4*)(out + (size_t)row * DIM);
    const float4* __restrict__ s2v = (const float4*)s2;
    const float4* __restrict__ s1v = (const float4*)s1;
    const float4* __restrict__ gtv = (const float4*)g_t;

    float f[64];
    float4* F = (float4*)f;

    // ---- load + s2 scale (layout A): 32 b128 loads in flight
#pragma unroll
    for (int r = 0; r < 16; ++r)
        F[r] = f4mul(xr[64 * r + lane], s2v[64 * r + lane]);

    // ---- FWHT1: (i,r) stages
    fwht_ri(F);

    // ---- transpose A->B: 16 ds_write_b128 (lane row contiguous), 64 ds_read_b32
#pragma unroll
    for (int r = 0; r < 16; ++r)
        L4[lane * (LSTR / 4) + r] = F[r];
#pragma unroll
    for (int m = 0; m < 64; ++m)
        f[m] = L[m * LSTR + lane];

    // ---- FWHT1: m stages (completes FWHT1)
    fwht_m(f);

    // ---- g multiply: g_t pre-transposed -> 16 contiguous float4 loads per lane
#pragma unroll
    for (int k = 0; k < 16; ++k)
        F[k] = f4mul(F[k], gtv[lane * 16 + k]);

    // ---- FWHT2: m stages
    fwht_m(f);

    // ---- transpose B->A: 16 ds_write_b128, 64 ds_read_b32
#pragma unroll
    for (int k = 0; k < 16; ++k)
        L4[lane * (LSTR / 4) + k] = F[k];
#pragma unroll
    for (int c = 0; c < 64; ++c)
        f[c] = L[c * LSTR + lane];

    // ---- FWHT2: (i,r) stages (completes FWHT2)
    fwht_ri(F);

    // ---- s1 scale + coalesced store (layout A)
#pragma unroll
    for (int r = 0; r < 16; ++r)
        orw[64 * r + lane] = f4mul(F[r], s1v[64 * r + lane]);
}

extern "C" void kernel_launch(void* const* d_in, const int* in_sizes, int n_in,
                              void* d_out, int out_size, void* d_ws, size_t ws_size,
                              hipStream_t stream) {
    // setup_inputs order: x, epsilon, s1, s2, g_mu, g_rho
    const float* x     = (const float*)d_in[0];
    const float* eps   = (const float*)d_in[1];
    const float* s1    = (const float*)d_in[2];
    const float* s2    = (const float*)d_in[3];
    const float* g_mu  = (const float*)d_in[4];
    const float* g_rho = (const float*)d_in[5];
    float* out = (float*)d_out;
    float* g_t = (float*)d_ws;   // 4096 floats = 16 KB scratch

    g_precompute<<<DIM / 256, 256, 0, stream>>>(eps, g_mu, g_rho, g_t);
    whvi_main<<<ROWS / 4, 256, 0, stream>>>(x, s1, s2, g_t, out);
}